// Round 1
// baseline (248.862 us; speedup 1.0000x reference)
//
#include <hip/hip_runtime.h>

// Problem constants (from reference):
//   N = 64 (protein length), B = 32 (batch), L = 2N-1 = 127 (lattice side)
//   out = (B, L, L, L) float32 = 65,548,256 elems ≈ 262 MB
// Work split:
//   1) hipMemsetAsync zeroes the lattice (dominant cost, write-BW bound)
//   2) scatter kernel: 2048 threads, one atomicAdd each (handles dup indices)

constexpr int PN = 64;
constexpr int PB = 32;
constexpr int PL = 2 * PN - 1;  // 127

__global__ void lattice_scatter_kernel(const float* __restrict__ acids,
                                       const int*   __restrict__ idx,
                                       const int*   __restrict__ mask,
                                       float*       __restrict__ out) {
    int t = blockIdx.x * blockDim.x + threadIdx.x;   // 0 .. B*N-1
    if (t >= PB * PN) return;
    if (mask[t] == 0) return;        // masked-off acids scatter 0 → no-op under add
    float v = acids[t];
    int b = t >> 6;                  // t / N  (N == 64)
    int i0 = idx[3 * t + 0] + (PN - 1);
    int i1 = idx[3 * t + 1] + (PN - 1);
    int i2 = idx[3 * t + 2] + (PN - 1);
    size_t off = ((((size_t)b * PL + i0) * PL) + i1) * PL + i2;
    atomicAdd(out + off, v);         // device-scope; handles index collisions
}

extern "C" void kernel_launch(void* const* d_in, const int* in_sizes, int n_in,
                              void* d_out, int out_size, void* d_ws, size_t ws_size,
                              hipStream_t stream) {
    const float* acids = (const float*)d_in[0];   // (B,N) f32
    const int*   idx   = (const int*)  d_in[1];   // (B,N,3) i32
    const int*   mask  = (const int*)  d_in[2];   // (B,N) bool -> i32 per harness
    float* out = (float*)d_out;

    // Zero the whole lattice (harness poisons d_out with 0xAA before each call).
    hipMemsetAsync(out, 0, (size_t)out_size * sizeof(float), stream);

    constexpr int total = PB * PN;   // 2048
    lattice_scatter_kernel<<<(total + 255) / 256, 256, 0, stream>>>(acids, idx, mask, out);
}

// Round 2
// 248.097 us; speedup vs baseline: 1.0031x; 1.0031x over previous
//
#include <hip/hip_runtime.h>

// Problem constants (from reference):
//   N = 64 (protein length), B = 32 (batch), L = 2N-1 = 127 (lattice side)
//   out = (B, L, L, L) float32 = 65,548,256 elems = 262,193,024 B (~262 MB)
//
// R1 evidence: rocclr fillBufferAligned (hipMemsetAsync) runs at ~10% occupancy,
// ~1.7 TB/s real write BW -> 157 us for the zero. Custom float4 zero kernel
// should hit the write-only HBM ceiling (~5-6.3 TB/s -> ~42-55 us).

constexpr int PN = 64;
constexpr int PB = 32;
constexpr int PL = 2 * PN - 1;  // 127
constexpr long long TOTAL_F = (long long)PB * PL * PL * PL;   // 65,548,256 (divisible by 4)
constexpr long long TOTAL_V4 = TOTAL_F / 4;                   // 16,387,064 float4s

__global__ void lattice_zero_kernel(float4* __restrict__ out) {
    long long t = (long long)blockIdx.x * blockDim.x + threadIdx.x;
    if (t < TOTAL_V4) {
        out[t] = make_float4(0.f, 0.f, 0.f, 0.f);
    }
}

__global__ void lattice_scatter_kernel(const float* __restrict__ acids,
                                       const int*   __restrict__ idx,
                                       const int*   __restrict__ mask,
                                       float*       __restrict__ out) {
    int t = blockIdx.x * blockDim.x + threadIdx.x;   // 0 .. B*N-1
    if (t >= PB * PN) return;
    if (mask[t] == 0) return;        // masked-off acids scatter 0 -> no-op under add
    float v = acids[t];
    int b = t >> 6;                  // t / N  (N == 64)
    int i0 = idx[3 * t + 0] + (PN - 1);
    int i1 = idx[3 * t + 1] + (PN - 1);
    int i2 = idx[3 * t + 2] + (PN - 1);
    size_t off = ((((size_t)b * PL + i0) * PL) + i1) * PL + i2;
    atomicAdd(out + off, v);         // device-scope; handles index collisions
}

extern "C" void kernel_launch(void* const* d_in, const int* in_sizes, int n_in,
                              void* d_out, int out_size, void* d_ws, size_t ws_size,
                              hipStream_t stream) {
    const float* acids = (const float*)d_in[0];   // (B,N) f32
    const int*   idx   = (const int*)  d_in[1];   // (B,N,3) i32
    const int*   mask  = (const int*)  d_in[2];   // (B,N) bool -> i32 per harness
    float* out = (float*)d_out;

    // Zero the lattice at full write bandwidth (one float4 store per thread).
    constexpr int ZB = 256;
    int zgrid = (int)((TOTAL_V4 + ZB - 1) / ZB);  // 64,013 blocks
    lattice_zero_kernel<<<zgrid, ZB, 0, stream>>>((float4*)out);

    // Scatter-add the 2048 masked values (stream-ordered after the zero).
    constexpr int total = PB * PN;   // 2048
    lattice_scatter_kernel<<<(total + 255) / 256, 256, 0, stream>>>(acids, idx, mask, out);
}